// Round 16
// baseline (912.445 us; speedup 1.0000x reference)
//
#include <hip/hip_runtime.h>
#include <math.h>

#define NP 256
#define HID 512
#define KB 16       // LU panel width (r16: 8 -> 16, halves panel count)

#if __has_attribute(amdgpu_num_vgpr)
#define FORCE_VGPR __attribute__((amdgpu_num_vgpr(256)))
#else
#define FORCE_VGPR
#endif

typedef short bf16x8 __attribute__((ext_vector_type(8)));
typedef float f32x4v __attribute__((ext_vector_type(4)));

// RNE bf16 with exact residual (v - bf16(v) is exactly representable).
__device__ __forceinline__ short bf16_rne(float v, float& rem) {
    unsigned u = __float_as_uint(v);
    unsigned r = (u + 0x7FFFu + ((u >> 16) & 1u)) & 0xFFFF0000u;
    rem = v - __uint_as_float(r);
    return (short)(r >> 16);
}
// 3-way RNE split: v = h + m + lo + r3, |r3| <= 2^-27 |v| (unbiased).
__device__ __forceinline__ void split3(float v, short& h, short& m, short& lo) {
    float r1, r2;
    h = bf16_rne(v, r1);
    m = bf16_rne(r1, r2);
    unsigned u2 = __float_as_uint(r2);
    lo = (short)((u2 + 0x7FFFu + ((u2 >> 16) & 1u)) >> 16);
}

// v3 MLP (byte-identical to round 15, passing): BT=128, 512 threads,
// 2 blocks/w; h0 split once into packed bf16 MFMA-A fragments in LDS;
// same-w block pair on same XCD 8 bids apart for W1 L2 reuse.
__global__ __launch_bounds__(512, 1) void k_mlp_v3(
    const float* __restrict__ x,  const float* __restrict__ W0,
    const float* __restrict__ b0, const float* __restrict__ W1,
    const float* __restrict__ b1, const float* __restrict__ W2,
    const float* __restrict__ b2, float* __restrict__ slater)
{
    __shared__ __align__(16) short pA[3][2][4][128][8];  // 48 KB
    __shared__ float s_red[8][128];                      // 4 KB
    const int bid  = blockIdx.x;
    const int xcd  = bid & 7;
    const int jj   = bid >> 3;
    const int half = jj & 1;
    const int w    = (xcd << 5) + (jj >> 1);
    const int tid  = threadIdx.x;
    const int wid  = tid >> 6;     // wave 0..7 -> f-slice wid*64
    const int l    = tid & 63;
    const int col  = l & 15;
    const int g    = l >> 4;
    const int fb   = wid * 64;

    f32x4v acc[8][4];
    #pragma unroll
    for (int bt = 0; bt < 8; ++bt)
        #pragma unroll
        for (int ft = 0; ft < 4; ++ft)
            acc[bt][ft] = (f32x4v){0.f, 0.f, 0.f, 0.f};

    // layer-0 mapping: 64 c x 128 b per phase, 16 per thread
    const int bb = tid & 127;
    const int co = tid >> 7;       // 0..3 (wave-pair uniform)
    const int bg = half*128 + bb;
    const float x0 = x[bg*3+0], x1 = x[bg*3+1], x2 = x[bg*3+2];
    const float* W0w = W0 + (size_t)w*3*HID;
    const float* b0w = b0 + (size_t)w*HID;
    const float* w1c = W1 + (size_t)w*HID*HID + fb + col;

    for (int ph = 0; ph < 8; ++ph) {
        if (ph) __syncthreads();
        // ---- layer 0: split h0 once into packed A-frags ----
        #pragma unroll 4
        for (int pass = 0; pass < 16; ++pass) {
            int cl = co + 4*pass;          // 0..63
            int c  = ph*64 + cl;
            float v = x0*W0w[c] + x1*W0w[HID+c] + x2*W0w[2*HID+c] + b0w[c];
            float t = tanhf(v);
            short h, m, lo; split3(t, h, m, lo);
            int ks = cl >> 5, r32 = cl & 31;
            int gg = (r32 >> 2) & 3;
            int jv = (r32 & 3) + 4*(r32 >> 4);
            pA[0][ks][gg][bb][jv] = h;
            pA[1][ks][gg][bb][jv] = m;
            pA[2][ks][gg][bb][jv] = lo;
        }
        __syncthreads();

        #pragma unroll
        for (int ks = 0; ks < 2; ++ks) {
            // ---- B: load f32 + split, all 4 ft (held live) ----
            bf16x8 Bh[4], Bm[4], Bl[4];
            const float* bkp = w1c + (size_t)(ph*64 + ks*32 + 4*g)*HID;
            #pragma unroll
            for (int ft = 0; ft < 4; ++ft)
                #pragma unroll
                for (int j = 0; j < 8; ++j) {
                    int koff = (j&3) + 16*(j>>2);
                    float v = bkp[(size_t)koff*HID + ft*16];
                    short h, m, lo; split3(v, h, m, lo);
                    Bh[ft][j] = h; Bm[ft][j] = m; Bl[ft][j] = lo;
                }
            // ---- A-frags in 2 chunks of 4 bt; 6-product MFMA ----
            #pragma unroll
            for (int btc = 0; btc < 2; ++btc) {
                bf16x8 Ah[4], Am[4], Al[4];
                #pragma unroll
                for (int b4 = 0; b4 < 4; ++b4) {
                    int row = (btc*4 + b4)*16 + col;
                    Ah[b4] = *reinterpret_cast<const bf16x8*>(&pA[0][ks][g][row][0]);
                    Am[b4] = *reinterpret_cast<const bf16x8*>(&pA[1][ks][g][row][0]);
                    Al[b4] = *reinterpret_cast<const bf16x8*>(&pA[2][ks][g][row][0]);
                }
                #pragma unroll
                for (int b4 = 0; b4 < 4; ++b4) {
                    const int bt = btc*4 + b4;
                    #pragma unroll
                    for (int ft = 0; ft < 4; ++ft) {
                        acc[bt][ft] = __builtin_amdgcn_mfma_f32_16x16x32_bf16(Ah[b4], Bh[ft], acc[bt][ft], 0,0,0);
                        acc[bt][ft] = __builtin_amdgcn_mfma_f32_16x16x32_bf16(Ah[b4], Bm[ft], acc[bt][ft], 0,0,0);
                        acc[bt][ft] = __builtin_amdgcn_mfma_f32_16x16x32_bf16(Am[b4], Bh[ft], acc[bt][ft], 0,0,0);
                        acc[bt][ft] = __builtin_amdgcn_mfma_f32_16x16x32_bf16(Ah[b4], Bl[ft], acc[bt][ft], 0,0,0);
                        acc[bt][ft] = __builtin_amdgcn_mfma_f32_16x16x32_bf16(Am[b4], Bm[ft], acc[bt][ft], 0,0,0);
                        acc[bt][ft] = __builtin_amdgcn_mfma_f32_16x16x32_bf16(Al[b4], Bh[ft], acc[bt][ft], 0,0,0);
                    }
                }
            }
        }
    }

    // ---- epilogue: tanh(acc+b1).W2, reduce over f, write slater row ----
    const float* b1w = b1 + (size_t)w*HID + fb;
    const float* W2w = W2 + (size_t)w*HID + fb;
    float bbv[4], wtv[4];
    #pragma unroll
    for (int ft = 0; ft < 4; ++ft) {
        bbv[ft] = b1w[ft*16 + col];
        wtv[ft] = W2w[ft*16 + col];
    }
    #pragma unroll
    for (int bt = 0; bt < 8; ++bt)
        #pragma unroll
        for (int r = 0; r < 4; ++r) {
            float part = 0.f;
            #pragma unroll
            for (int ft = 0; ft < 4; ++ft)
                part += tanhf(acc[bt][ft][r] + bbv[ft]) * wtv[ft];
            part += __shfl_xor(part, 1); part += __shfl_xor(part, 2);
            part += __shfl_xor(part, 4); part += __shfl_xor(part, 8);
            if (col == 0) s_red[wid][bt*16 + g*4 + r] = part;
        }
    __syncthreads();
    if (tid < 128) {
        float s = 0.f;
        #pragma unroll
        for (int wd = 0; wd < 8; ++wd) s += s_red[wd][tid];
        slater[w*NP + half*128 + tid] = s + b2[w];
    }
}

__device__ __forceinline__ float rf_f32(float x) {
    return __uint_as_float(__builtin_amdgcn_readfirstlane(__float_as_uint(x)));
}
__device__ __forceinline__ float rl_f32(float x, int lane) {
    return __uint_as_float(__builtin_amdgcn_readlane(__float_as_uint(x), lane));
}
template<int CTRL>
__device__ __forceinline__ unsigned dpp_u32(unsigned v) {
    return (unsigned)__builtin_amdgcn_update_dpp(0, (int)v, CTRL, 0xF, 0xF, true);
}

// Blocked partially-pivoted f32 LU, matrix register-resident.
// r16: KB 8 -> 16. FP-bit-identical to the verified rank-1 chain (TRSM
// reproduces incremental updates; per-element update order is m-ascending
// in both) -> pivots and absmax unchanged. Halves panels (16), barriers
// (80 vs 160), and all fixed per-panel serial costs. STEP5 m-outer with
// 4-reg Lm (was 64-reg L0). amdgpu_num_vgpr(256) hint to keep a[4][32]
// in arch VGPRs (r15 showed VGPR=116 -> AGPR copy churn).
__global__ __launch_bounds__(512, 1) FORCE_VGPR void k_lu_blk(
    const float* __restrict__ A, float* __restrict__ out)
{
    const int tid  = threadIdx.x;
    const int ln   = tid & 63;      // lane: row-in-quarter
    const int wv   = tid >> 6;      // wave id = 32-col slice (wave-uniform)
    const int cb   = wv * 32;       // col base

    __shared__ float s_panel[NP][KB+1];   // stride 17 (odd): conflict-free
    __shared__ float s_stage[2*KB][260];  // staged rows (full 256 cols + pad)
    __shared__ float s_U[KB][260];        // TRSM'd U block
    __shared__ int   s_src[NP];
    __shared__ int   s_p[KB];
    __shared__ int   s_uslot[KB];
    __shared__ float s_piv[NP];

    float a[4][32];                       // rows q*64+ln, cols cb..cb+31
    {
        const float4* Ap = reinterpret_cast<const float4*>(A);
        #pragma unroll
        for (int q = 0; q < 4; ++q)
            #pragma unroll
            for (int u = 0; u < 8; ++u) {
                float4 v = Ap[(q*64+ln)*64 + wv*8 + u];
                a[q][u*4+0]=v.x; a[q][u*4+1]=v.y; a[q][u*4+2]=v.z; a[q][u*4+3]=v.w;
            }
    }

    for (int pi = 0; pi < NP/KB; ++pi) {
        const int k0 = pi * KB;
        __syncthreads();                                  // B0

        // ---- STEP 1: stage panel cols (16) + init s_src ----
        if (tid < 256) s_src[tid] = tid;
        if (wv == (k0 >> 5)) {                            // wave-uniform
            if (((k0 >> 4) & 1) == 0) {
                #pragma unroll
                for (int q = 0; q < 4; ++q)
                    #pragma unroll
                    for (int c = 0; c < KB; ++c) s_panel[q*64+ln][c] = a[q][c];
            } else {
                #pragma unroll
                for (int q = 0; q < 4; ++q)
                    #pragma unroll
                    for (int c = 0; c < KB; ++c) s_panel[q*64+ln][c] = a[q][16+c];
            }
        }
        __syncthreads();                                  // B1

        // ---- STEP 2: wave 0 factorizes the 256x16 panel (LDS-free core) ----
        if (tid < 64) {
            const int lane = tid;
            float pa[4][KB];
            int   lid[4];                  // logical position of slot q's row
            #pragma unroll
            for (int q = 0; q < 4; ++q) {
                lid[q] = q*64 + lane;
                #pragma unroll
                for (int c = 0; c < KB; ++c) pa[q][c] = s_panel[q*64+lane][c];
            }

            int pvt[KB];
            #pragma unroll
            for (int kk = 0; kk < KB; ++kk) {
                const int k = k0 + kk;
                // packed-key candidates: top-24 bits of |v| | (255 - lid)
                unsigned key = 0u;
                #pragma unroll
                for (int q = 0; q < 4; ++q) {
                    unsigned ab = __float_as_uint(pa[q][kk]) & 0x7FFFFFFFu;
                    unsigned kq = (ab & 0xFFFFFF00u) | (unsigned)(255 - lid[q]);
                    if (lid[q] >= k && kq > key) key = kq;
                }
                // 6-step DPP max-reduce -> lane 63 holds global max
                { unsigned t;
                  t = dpp_u32<0x111>(key); if (t > key) key = t;   // row_shr:1
                  t = dpp_u32<0x112>(key); if (t > key) key = t;   // row_shr:2
                  t = dpp_u32<0x114>(key); if (t > key) key = t;   // row_shr:4
                  t = dpp_u32<0x118>(key); if (t > key) key = t;   // row_shr:8
                  t = dpp_u32<0x142>(key); if (t > key) key = t;   // row_bcast:15
                  t = dpp_u32<0x143>(key); if (t > key) key = t;   // row_bcast:31
                }
                const unsigned gk = (unsigned)__builtin_amdgcn_readlane((int)key, 63);
                const int p = 255 - (int)(gk & 0xFFu);   // logical pivot row
                pvt[kk] = p;
                // physical holder of logical row p: (plane, pslot)
                int myslot = -1;
                #pragma unroll
                for (int q = 0; q < 4; ++q) if (lid[q] == p) myslot = q;
                unsigned long long bal = __ballot(myslot >= 0);
                const int plane = (int)__ffsll((long long)bal) - 1;
                const int pslot = __builtin_amdgcn_readlane(myslot, plane);
                // pivot-row broadcast (KB independent readlanes)
                float urow[KB];
                #pragma unroll
                for (int c = 0; c < KB; ++c) {
                    float t = (pslot==0) ? pa[0][c] : (pslot==1) ? pa[1][c]
                            : (pslot==2) ? pa[2][c] : pa[3][c];
                    urow[c] = rl_f32(t, plane);
                }
                // lazy swap of logical ids
                #pragma unroll
                for (int q = 0; q < 4; ++q) {
                    int lq = lid[q];
                    lid[q] = (lq == k) ? p : (lq == p) ? k : lq;
                }
                const float pv = urow[kk];
                if (lane == 0) s_piv[k] = (p != k) ? -pv : pv;
                const float rp = rf_f32(1.0f / pv);
                #pragma unroll
                for (int q = 0; q < 4; ++q)
                    if (lid[q] > k) pa[q][kk] *= rp;
                #pragma unroll
                for (int c = kk+1; c < KB; ++c) {
                    #pragma unroll
                    for (int q = 0; q < 4; ++q)
                        if (lid[q] > k) pa[q][c] = fmaf(-pa[q][kk], urow[c], pa[q][c]);
                }
            }
            // write back factored panel BY LOGICAL INDEX + pivots
            #pragma unroll
            for (int q = 0; q < 4; ++q)
                #pragma unroll
                for (int c = 0; c < KB; ++c) s_panel[lid[q]][c] = pa[q][c];
            if (lane == 0) {
                #pragma unroll
                for (int s = 0; s < KB; ++s) s_p[s] = pvt[s];
            }
            // in-register swap simulation on 32 tracked positions
            const int l16 = lane - 16;
            int psel = pvt[0];
            #pragma unroll
            for (int s = 1; s < KB; ++s) psel = (l16 == s) ? pvt[s] : psel;
            const int mypos = (lane < KB) ? (k0 + lane) : psel;
            int cur = mypos;
            #pragma unroll
            for (int s = 0; s < KB; ++s) {
                int cA = __builtin_amdgcn_readlane(cur, s);      // content at k0+s
                int cB = __builtin_amdgcn_readlane(cur, KB+s);   // content at pvt[s]
                int ks = k0 + s, ps = pvt[s];
                if (mypos == ks) cur = cB;
                else if (mypos == ps) cur = cA;
            }
            if (lane < 2*KB) s_src[mypos] = cur;
            if (lane < KB) {
                int c = cur, slot = KB;
                #pragma unroll
                for (int s = 0; s < KB; ++s) slot = (pvt[s]==c) ? KB+s : slot;
                if (c >= k0 && c < k0+KB) slot = c - k0;
                s_uslot[lane] = slot;
            }
        }
        __syncthreads();                                  // B2

        int pp[KB];
        #pragma unroll
        for (int s = 0; s < KB; ++s) pp[s] = s_p[s];

        // ---- STEP 3: stage affected rows (pre-swap content, by position) ----
        #pragma unroll
        for (int q = 0; q < 4; ++q) {
            const int iq = q*64 + ln;
            if (iq >= k0 && iq < k0+KB) {
                const int sl = iq - k0;
                #pragma unroll
                for (int u = 0; u < 8; ++u) {
                    float4 v; v.x=a[q][u*4+0]; v.y=a[q][u*4+1];
                    v.z=a[q][u*4+2]; v.w=a[q][u*4+3];
                    *reinterpret_cast<float4*>(&s_stage[sl][cb + u*4]) = v;
                }
            }
            #pragma unroll
            for (int s = 0; s < KB; ++s) {
                if (iq == pp[s]) {
                    #pragma unroll
                    for (int u = 0; u < 8; ++u) {
                        float4 v; v.x=a[q][u*4+0]; v.y=a[q][u*4+1];
                        v.z=a[q][u*4+2]; v.w=a[q][u*4+3];
                        *reinterpret_cast<float4*>(&s_stage[KB+s][cb + u*4]) = v;
                    }
                }
            }
        }
        __syncthreads();                                  // B3

        // ---- STEP 4a: apply row permutation from stage ----
        #pragma unroll
        for (int q = 0; q < 4; ++q) {
            const int iq = q*64 + ln;
            const int sr = s_src[iq];
            if (sr != iq) {
                int slot = KB;
                #pragma unroll
                for (int s = 0; s < KB; ++s) slot = (pp[s]==sr) ? KB+s : slot;
                if (sr >= k0 && sr < k0+KB) slot = sr - k0;
                #pragma unroll
                for (int u = 0; u < 8; ++u) {
                    float4 v = *reinterpret_cast<const float4*>(&s_stage[slot][cb + u*4]);
                    a[q][u*4+0]=v.x; a[q][u*4+1]=v.y; a[q][u*4+2]=v.z; a[q][u*4+3]=v.w;
                }
            }
        }
        // ---- STEP 4b: TRSM of U block, column-parallel (tid<256, col j=tid) ----
        if (tid < 256) {
            const int j = tid;
            int us[KB];
            #pragma unroll
            for (int m = 0; m < KB; ++m) us[m] = s_uslot[m];
            float uv[KB];
            #pragma unroll
            for (int m = 0; m < KB; ++m) {
                float v = s_stage[us[m]][j];
                #pragma unroll
                for (int s = 0; s < KB; ++s)
                    if (s < m) v = fmaf(-s_panel[k0+m][s], uv[s], v);
                uv[m] = v;
                s_U[m][j] = v;
            }
        }
        __syncthreads();                                  // B4

        // ---- STEP 5: rank-16 trailing update, m-outer (per-element order
        //      m-ascending == rank-1 chain; Lm is 4 regs vs 64) ----
        if (cb + 31 >= k0 + KB) {                         // wave-uniform
            #pragma unroll
            for (int m = 0; m < KB; ++m) {
                float Lm[4];
                #pragma unroll
                for (int q = 0; q < 4; ++q) Lm[q] = s_panel[q*64+ln][m];
                #pragma unroll
                for (int u4 = 0; u4 < 8; ++u4) {
                    if (cb + u4*4 + 3 >= k0 + KB) {       // wave-uniform
                        const float4 uvv = *reinterpret_cast<const float4*>(&s_U[m][cb + u4*4]);
                        #pragma unroll
                        for (int q = 0; q < 4; ++q) {
                            if (q*64 + 63 >= k0 + KB) {   // wave-uniform
                                a[q][u4*4+0] = fmaf(-Lm[q], uvv.x, a[q][u4*4+0]);
                                a[q][u4*4+1] = fmaf(-Lm[q], uvv.y, a[q][u4*4+1]);
                                a[q][u4*4+2] = fmaf(-Lm[q], uvv.z, a[q][u4*4+2]);
                                a[q][u4*4+3] = fmaf(-Lm[q], uvv.w, a[q][u4*4+3]);
                            }
                        }
                    }
                }
            }
        }
    }
    __syncthreads();

    // ---- logdet = sum log|piv| (f64 accum), sign = parity of negatives ----
    if (tid < 64) {
        double ld = 0.0; int neg = 0;
        #pragma unroll
        for (int q = 0; q < 4; ++q) {
            float pv = s_piv[q*64 + tid];
            ld  += (double)logf(fabsf(pv));
            neg ^= (pv < 0.0f) ? 1 : 0;
        }
        #pragma unroll
        for (int off = 32; off; off >>= 1) {
            ld  += __shfl_xor(ld, off);
            neg ^= __shfl_xor(neg, off);
        }
        if (tid == 0) { out[0] = neg ? -1.0f : 1.0f; out[1] = (float)ld; }
    }
}

extern "C" void kernel_launch(void* const* d_in, const int* in_sizes, int n_in,
                              void* d_out, int out_size, void* d_ws, size_t ws_size,
                              hipStream_t stream)
{
    const float* x  = (const float*)d_in[0];
    const float* W0 = (const float*)d_in[1];
    const float* b0 = (const float*)d_in[2];
    const float* W1 = (const float*)d_in[3];
    const float* b1 = (const float*)d_in[4];
    const float* W2 = (const float*)d_in[5];
    const float* b2 = (const float*)d_in[6];
    float* out    = (float*)d_out;
    float* slater = (float*)d_ws;           // 256*256*4 = 256 KB scratch

    k_mlp_v3<<<512, 512, 0, stream>>>(x, W0, b0, W1, b1, W2, b2, slater);
    k_lu_blk<<<1, 512, 0, stream>>>(slater, out);
}

// Round 17
// 690.837 us; speedup vs baseline: 1.3208x; 1.3208x over previous
//
#include <hip/hip_runtime.h>
#include <math.h>

#define NP 256
#define HID 512
#define KB 8        // LU panel width (reverted: KB=16 spilled, r16 WRITE=70KB)

typedef short bf16x8 __attribute__((ext_vector_type(8)));
typedef float f32x4v __attribute__((ext_vector_type(4)));

// RNE bf16 with exact residual (v - bf16(v) is exactly representable).
__device__ __forceinline__ short bf16_rne(float v, float& rem) {
    unsigned u = __float_as_uint(v);
    unsigned r = (u + 0x7FFFu + ((u >> 16) & 1u)) & 0xFFFF0000u;
    rem = v - __uint_as_float(r);
    return (short)(r >> 16);
}
// 3-way RNE split: v = h + m + lo + r3, |r3| <= 2^-27 |v| (unbiased).
__device__ __forceinline__ void split3(float v, short& h, short& m, short& lo) {
    float r1, r2;
    h = bf16_rne(v, r1);
    m = bf16_rne(r1, r2);
    unsigned u2 = __float_as_uint(r2);
    lo = (short)((u2 + 0x7FFFu + ((u2 >> 16) & 1u)) >> 16);
}

// v3 MLP (byte-identical to rounds 15/16, passing): BT=128, 512 threads,
// 2 blocks/w; h0 split once into packed bf16 MFMA-A fragments in LDS;
// same-w block pair on same XCD 8 bids apart for W1 L2 reuse.
__global__ __launch_bounds__(512, 1) void k_mlp_v3(
    const float* __restrict__ x,  const float* __restrict__ W0,
    const float* __restrict__ b0, const float* __restrict__ W1,
    const float* __restrict__ b1, const float* __restrict__ W2,
    const float* __restrict__ b2, float* __restrict__ slater)
{
    __shared__ __align__(16) short pA[3][2][4][128][8];  // 48 KB
    __shared__ float s_red[8][128];                      // 4 KB
    const int bid  = blockIdx.x;
    const int xcd  = bid & 7;
    const int jj   = bid >> 3;
    const int half = jj & 1;
    const int w    = (xcd << 5) + (jj >> 1);
    const int tid  = threadIdx.x;
    const int wid  = tid >> 6;     // wave 0..7 -> f-slice wid*64
    const int l    = tid & 63;
    const int col  = l & 15;
    const int g    = l >> 4;
    const int fb   = wid * 64;

    f32x4v acc[8][4];
    #pragma unroll
    for (int bt = 0; bt < 8; ++bt)
        #pragma unroll
        for (int ft = 0; ft < 4; ++ft)
            acc[bt][ft] = (f32x4v){0.f, 0.f, 0.f, 0.f};

    // layer-0 mapping: 64 c x 128 b per phase, 16 per thread
    const int bb = tid & 127;
    const int co = tid >> 7;       // 0..3 (wave-pair uniform)
    const int bg = half*128 + bb;
    const float x0 = x[bg*3+0], x1 = x[bg*3+1], x2 = x[bg*3+2];
    const float* W0w = W0 + (size_t)w*3*HID;
    const float* b0w = b0 + (size_t)w*HID;
    const float* w1c = W1 + (size_t)w*HID*HID + fb + col;

    for (int ph = 0; ph < 8; ++ph) {
        if (ph) __syncthreads();
        // ---- layer 0: split h0 once into packed A-frags ----
        #pragma unroll 4
        for (int pass = 0; pass < 16; ++pass) {
            int cl = co + 4*pass;          // 0..63
            int c  = ph*64 + cl;
            float v = x0*W0w[c] + x1*W0w[HID+c] + x2*W0w[2*HID+c] + b0w[c];
            float t = tanhf(v);
            short h, m, lo; split3(t, h, m, lo);
            int ks = cl >> 5, r32 = cl & 31;
            int gg = (r32 >> 2) & 3;
            int jv = (r32 & 3) + 4*(r32 >> 4);
            pA[0][ks][gg][bb][jv] = h;
            pA[1][ks][gg][bb][jv] = m;
            pA[2][ks][gg][bb][jv] = lo;
        }
        __syncthreads();

        #pragma unroll
        for (int ks = 0; ks < 2; ++ks) {
            // ---- B: load f32 + split, all 4 ft (held live) ----
            bf16x8 Bh[4], Bm[4], Bl[4];
            const float* bkp = w1c + (size_t)(ph*64 + ks*32 + 4*g)*HID;
            #pragma unroll
            for (int ft = 0; ft < 4; ++ft)
                #pragma unroll
                for (int j = 0; j < 8; ++j) {
                    int koff = (j&3) + 16*(j>>2);
                    float v = bkp[(size_t)koff*HID + ft*16];
                    short h, m, lo; split3(v, h, m, lo);
                    Bh[ft][j] = h; Bm[ft][j] = m; Bl[ft][j] = lo;
                }
            // ---- A-frags in 2 chunks of 4 bt; 6-product MFMA ----
            #pragma unroll
            for (int btc = 0; btc < 2; ++btc) {
                bf16x8 Ah[4], Am[4], Al[4];
                #pragma unroll
                for (int b4 = 0; b4 < 4; ++b4) {
                    int row = (btc*4 + b4)*16 + col;
                    Ah[b4] = *reinterpret_cast<const bf16x8*>(&pA[0][ks][g][row][0]);
                    Am[b4] = *reinterpret_cast<const bf16x8*>(&pA[1][ks][g][row][0]);
                    Al[b4] = *reinterpret_cast<const bf16x8*>(&pA[2][ks][g][row][0]);
                }
                #pragma unroll
                for (int b4 = 0; b4 < 4; ++b4) {
                    const int bt = btc*4 + b4;
                    #pragma unroll
                    for (int ft = 0; ft < 4; ++ft) {
                        acc[bt][ft] = __builtin_amdgcn_mfma_f32_16x16x32_bf16(Ah[b4], Bh[ft], acc[bt][ft], 0,0,0);
                        acc[bt][ft] = __builtin_amdgcn_mfma_f32_16x16x32_bf16(Ah[b4], Bm[ft], acc[bt][ft], 0,0,0);
                        acc[bt][ft] = __builtin_amdgcn_mfma_f32_16x16x32_bf16(Am[b4], Bh[ft], acc[bt][ft], 0,0,0);
                        acc[bt][ft] = __builtin_amdgcn_mfma_f32_16x16x32_bf16(Ah[b4], Bl[ft], acc[bt][ft], 0,0,0);
                        acc[bt][ft] = __builtin_amdgcn_mfma_f32_16x16x32_bf16(Am[b4], Bm[ft], acc[bt][ft], 0,0,0);
                        acc[bt][ft] = __builtin_amdgcn_mfma_f32_16x16x32_bf16(Al[b4], Bh[ft], acc[bt][ft], 0,0,0);
                    }
                }
            }
        }
    }

    // ---- epilogue: tanh(acc+b1).W2, reduce over f, write slater row ----
    const float* b1w = b1 + (size_t)w*HID + fb;
    const float* W2w = W2 + (size_t)w*HID + fb;
    float bbv[4], wtv[4];
    #pragma unroll
    for (int ft = 0; ft < 4; ++ft) {
        bbv[ft] = b1w[ft*16 + col];
        wtv[ft] = W2w[ft*16 + col];
    }
    #pragma unroll
    for (int bt = 0; bt < 8; ++bt)
        #pragma unroll
        for (int r = 0; r < 4; ++r) {
            float part = 0.f;
            #pragma unroll
            for (int ft = 0; ft < 4; ++ft)
                part += tanhf(acc[bt][ft][r] + bbv[ft]) * wtv[ft];
            part += __shfl_xor(part, 1); part += __shfl_xor(part, 2);
            part += __shfl_xor(part, 4); part += __shfl_xor(part, 8);
            if (col == 0) s_red[wid][bt*16 + g*4 + r] = part;
        }
    __syncthreads();
    if (tid < 128) {
        float s = 0.f;
        #pragma unroll
        for (int wd = 0; wd < 8; ++wd) s += s_red[wd][tid];
        slater[w*NP + half*128 + tid] = s + b2[w];
    }
}

__device__ __forceinline__ float rf_f32(float x) {
    return __uint_as_float(__builtin_amdgcn_readfirstlane(__float_as_uint(x)));
}
__device__ __forceinline__ float rl_f32(float x, int lane) {
    return __uint_as_float(__builtin_amdgcn_readlane(__float_as_uint(x), lane));
}
template<int CTRL>
__device__ __forceinline__ unsigned dpp_u32(unsigned v) {
    return (unsigned)__builtin_amdgcn_update_dpp(0, (int)v, CTRL, 0xF, 0xF, true);
}

// Blocked (KB=8) partially-pivoted f32 LU with PANEL LOOKAHEAD.
// r17 vs r15: double-buffered s_panel; per panel: [STEP3] B3 [4a + TRSM] B4
// [STEP5a: owner wave updates next-panel cols + stages them + s_src init]
// B5 [wave0: STEP2(next) CONCURRENT with all-wave STEP5b (cols >= k0+16)]
// B6. 4 barriers/panel (was 5); STEP2 hidden under STEP5b for pi>=3; the
// useless final panel iteration dropped (only its pivots matter, produced
// by STEP2(31) inside pi=30). 5a/5b partition on the 8-aligned boundary
// with the same m-ascending per-element order -> FP-bit-identical to r15:
// absmax must stay exactly 64.0.
__global__ __launch_bounds__(512, 1) void k_lu_blk(const float* __restrict__ A,
                                                   float* __restrict__ out)
{
    const int tid  = threadIdx.x;
    const int ln   = tid & 63;      // lane: row-in-quarter
    const int wv   = tid >> 6;      // wave id = 32-col slice (wave-uniform)
    const int cb   = wv * 32;       // col base

    __shared__ float s_panel[2][NP][KB+1];  // double-buffered, stride 9
    __shared__ float s_stage[2*KB][260];
    __shared__ float s_U[KB][260];
    __shared__ int   s_src[NP];
    __shared__ int   s_p[KB];
    __shared__ int   s_uslot[KB];
    __shared__ float s_piv[NP];

    float a[4][32];                       // rows q*64+ln, cols cb..cb+31
    {
        const float4* Ap = reinterpret_cast<const float4*>(A);
        #pragma unroll
        for (int q = 0; q < 4; ++q)
            #pragma unroll
            for (int u = 0; u < 8; ++u) {
                float4 v = Ap[(q*64+ln)*64 + wv*8 + u];
                a[q][u*4+0]=v.x; a[q][u*4+1]=v.y; a[q][u*4+2]=v.z; a[q][u*4+3]=v.w;
            }
    }

    // stage cols [k0s, k0s+8) of this wave's slice into spnl (caller guards wave)
    auto STAGE = [&](int k0s, float (*spnl)[KB+1]) {
        switch ((k0s & 31) >> 3) {
            case 0:
                #pragma unroll
                for (int q = 0; q < 4; ++q)
                    #pragma unroll
                    for (int c = 0; c < KB; ++c) spnl[q*64+ln][c] = a[q][c];
                break;
            case 1:
                #pragma unroll
                for (int q = 0; q < 4; ++q)
                    #pragma unroll
                    for (int c = 0; c < KB; ++c) spnl[q*64+ln][c] = a[q][8+c];
                break;
            case 2:
                #pragma unroll
                for (int q = 0; q < 4; ++q)
                    #pragma unroll
                    for (int c = 0; c < KB; ++c) spnl[q*64+ln][c] = a[q][16+c];
                break;
            default:
                #pragma unroll
                for (int q = 0; q < 4; ++q)
                    #pragma unroll
                    for (int c = 0; c < KB; ++c) spnl[q*64+ln][c] = a[q][24+c];
                break;
        }
    };

    // wave-0 panel factorization (verbatim r15 STEP2, parametrized by buffer)
    auto STEP2 = [&](int k0, float (*spnl)[KB+1]) {
        const int lane = tid;
        float pa[4][KB];
        int   lid[4];
        #pragma unroll
        for (int q = 0; q < 4; ++q) {
            lid[q] = q*64 + lane;
            #pragma unroll
            for (int c = 0; c < KB; ++c) pa[q][c] = spnl[q*64+lane][c];
        }
        int pvt[KB];
        #pragma unroll
        for (int kk = 0; kk < KB; ++kk) {
            const int k = k0 + kk;
            unsigned key = 0u;
            #pragma unroll
            for (int q = 0; q < 4; ++q) {
                unsigned ab = __float_as_uint(pa[q][kk]) & 0x7FFFFFFFu;
                unsigned kq = (ab & 0xFFFFFF00u) | (unsigned)(255 - lid[q]);
                if (lid[q] >= k && kq > key) key = kq;
            }
            { unsigned t;
              t = dpp_u32<0x111>(key); if (t > key) key = t;
              t = dpp_u32<0x112>(key); if (t > key) key = t;
              t = dpp_u32<0x114>(key); if (t > key) key = t;
              t = dpp_u32<0x118>(key); if (t > key) key = t;
              t = dpp_u32<0x142>(key); if (t > key) key = t;
              t = dpp_u32<0x143>(key); if (t > key) key = t;
            }
            const unsigned gk = (unsigned)__builtin_amdgcn_readlane((int)key, 63);
            const int p = 255 - (int)(gk & 0xFFu);
            pvt[kk] = p;
            int myslot = -1;
            #pragma unroll
            for (int q = 0; q < 4; ++q) if (lid[q] == p) myslot = q;
            unsigned long long bal = __ballot(myslot >= 0);
            const int plane = (int)__ffsll((long long)bal) - 1;
            const int pslot = __builtin_amdgcn_readlane(myslot, plane);
            float urow[KB];
            #pragma unroll
            for (int c = 0; c < KB; ++c) {
                float t = (pslot==0) ? pa[0][c] : (pslot==1) ? pa[1][c]
                        : (pslot==2) ? pa[2][c] : pa[3][c];
                urow[c] = rl_f32(t, plane);
            }
            #pragma unroll
            for (int q = 0; q < 4; ++q) {
                int lq = lid[q];
                lid[q] = (lq == k) ? p : (lq == p) ? k : lq;
            }
            const float pv = urow[kk];
            if (lane == 0) s_piv[k] = (p != k) ? -pv : pv;
            const float rp = rf_f32(1.0f / pv);
            #pragma unroll
            for (int q = 0; q < 4; ++q)
                if (lid[q] > k) pa[q][kk] *= rp;
            #pragma unroll
            for (int c = kk+1; c < KB; ++c) {
                #pragma unroll
                for (int q = 0; q < 4; ++q)
                    if (lid[q] > k) pa[q][c] = fmaf(-pa[q][kk], urow[c], pa[q][c]);
            }
        }
        #pragma unroll
        for (int q = 0; q < 4; ++q)
            #pragma unroll
            for (int c = 0; c < KB; ++c) spnl[lid[q]][c] = pa[q][c];
        if (lane == 0) {
            s_p[0]=pvt[0]; s_p[1]=pvt[1]; s_p[2]=pvt[2]; s_p[3]=pvt[3];
            s_p[4]=pvt[4]; s_p[5]=pvt[5]; s_p[6]=pvt[6]; s_p[7]=pvt[7];
        }
        // in-register swap simulation on 16 tracked positions
        int l8 = lane - 8;
        int psel = pvt[0];
        psel = (l8==1)?pvt[1]:psel; psel = (l8==2)?pvt[2]:psel;
        psel = (l8==3)?pvt[3]:psel; psel = (l8==4)?pvt[4]:psel;
        psel = (l8==5)?pvt[5]:psel; psel = (l8==6)?pvt[6]:psel;
        psel = (l8==7)?pvt[7]:psel;
        const int mypos = (lane < 8) ? (k0 + lane) : psel;
        int cur = mypos;
        #pragma unroll
        for (int s = 0; s < KB; ++s) {
            int cA = __builtin_amdgcn_readlane(cur, s);
            int cB = __builtin_amdgcn_readlane(cur, 8+s);
            int ks = k0 + s, ps = pvt[s];
            if (mypos == ks) cur = cB;
            else if (mypos == ps) cur = cA;
        }
        if (lane < 16) s_src[mypos] = cur;
        if (lane < 8) {
            int c = cur, slot = 8;
            slot = (pvt[0]==c)? 8:slot; slot = (pvt[1]==c)? 9:slot;
            slot = (pvt[2]==c)?10:slot; slot = (pvt[3]==c)?11:slot;
            slot = (pvt[4]==c)?12:slot; slot = (pvt[5]==c)?13:slot;
            slot = (pvt[6]==c)?14:slot; slot = (pvt[7]==c)?15:slot;
            if (c >= k0 && c < k0+KB) slot = c - k0;
            s_uslot[lane] = slot;
        }
    };

    // ---- prologue: stage + factorize panel 0 ----
    if (tid < 256) s_src[tid] = tid;
    if (wv == 0) STAGE(0, s_panel[0]);
    __syncthreads();
    if (tid < 64) STEP2(0, s_panel[0]);
    __syncthreads();

    for (int pi = 0; pi < 31; ++pi) {
        const int k0  = pi * KB;
        const int buf = pi & 1;
        const int nk  = k0 + KB;

        int pp[KB];
        #pragma unroll
        for (int s = 0; s < KB; ++s) pp[s] = s_p[s];

        // ---- STEP 3: stage affected rows (pre-swap content, by position) ----
        #pragma unroll
        for (int q = 0; q < 4; ++q) {
            const int iq = q*64 + ln;
            if (iq >= k0 && iq < nk) {
                const int sl = iq - k0;
                #pragma unroll
                for (int u = 0; u < 8; ++u) {
                    float4 v; v.x=a[q][u*4+0]; v.y=a[q][u*4+1];
                    v.z=a[q][u*4+2]; v.w=a[q][u*4+3];
                    *reinterpret_cast<float4*>(&s_stage[sl][cb + u*4]) = v;
                }
            }
            #pragma unroll
            for (int s = 0; s < KB; ++s) {
                if (iq == pp[s]) {
                    #pragma unroll
                    for (int u = 0; u < 8; ++u) {
                        float4 v; v.x=a[q][u*4+0]; v.y=a[q][u*4+1];
                        v.z=a[q][u*4+2]; v.w=a[q][u*4+3];
                        *reinterpret_cast<float4*>(&s_stage[KB+s][cb + u*4]) = v;
                    }
                }
            }
        }
        __syncthreads();                                  // B3

        // ---- STEP 4a: apply row permutation from stage ----
        #pragma unroll
        for (int q = 0; q < 4; ++q) {
            const int iq = q*64 + ln;
            const int sr = s_src[iq];
            if (sr != iq) {
                int slot = KB;
                #pragma unroll
                for (int s = 0; s < KB; ++s) slot = (pp[s]==sr) ? KB+s : slot;
                if (sr >= k0 && sr < nk) slot = sr - k0;
                #pragma unroll
                for (int u = 0; u < 8; ++u) {
                    float4 v = *reinterpret_cast<const float4*>(&s_stage[slot][cb + u*4]);
                    a[q][u*4+0]=v.x; a[q][u*4+1]=v.y; a[q][u*4+2]=v.z; a[q][u*4+3]=v.w;
                }
            }
        }
        // ---- STEP 4b: TRSM of U block, column-parallel (tid<256) ----
        if (tid < 256) {
            const int j = tid;
            int us[KB];
            #pragma unroll
            for (int m = 0; m < KB; ++m) us[m] = s_uslot[m];
            float uv[KB];
            #pragma unroll
            for (int m = 0; m < KB; ++m) {
                float v = s_stage[us[m]][j];
                #pragma unroll
                for (int s = 0; s < KB; ++s)
                    if (s < m) v = fmaf(-s_panel[buf][k0+m][s], uv[s], v);
                uv[m] = v;
                s_U[m][j] = v;
            }
        }
        __syncthreads();                                  // B4

        // ---- STEP 5a: owner wave updates next-panel cols [nk, nk+8),
        //      stages them into s_panel[buf^1]; s_src re-init ----
        if (tid < 256) s_src[tid] = tid;
        if (wv == (nk >> 5)) {
            float L0[4][KB];
            #pragma unroll
            for (int q = 0; q < 4; ++q)
                #pragma unroll
                for (int m = 0; m < KB; ++m) L0[q][m] = s_panel[buf][q*64+ln][m];
            #pragma unroll
            for (int u4 = 0; u4 < 8; ++u4) {
                if (cb + u4*4 >= nk && cb + u4*4 < nk + KB) {   // wave-uniform
                    #pragma unroll
                    for (int m = 0; m < KB; ++m) {
                        const float4 uvv = *reinterpret_cast<const float4*>(&s_U[m][cb + u4*4]);
                        #pragma unroll
                        for (int q = 0; q < 4; ++q) {
                            if (q*64 + 63 >= nk) {              // wave-uniform
                                a[q][u4*4+0] = fmaf(-L0[q][m], uvv.x, a[q][u4*4+0]);
                                a[q][u4*4+1] = fmaf(-L0[q][m], uvv.y, a[q][u4*4+1]);
                                a[q][u4*4+2] = fmaf(-L0[q][m], uvv.z, a[q][u4*4+2]);
                                a[q][u4*4+3] = fmaf(-L0[q][m], uvv.w, a[q][u4*4+3]);
                            }
                        }
                    }
                }
            }
            STAGE(nk, s_panel[buf ^ 1]);
        }
        __syncthreads();                                  // B5

        // ---- wave0: STEP2(next panel)  ||  all waves: STEP5b ----
        if (tid < 64) STEP2(nk, s_panel[buf ^ 1]);
        if (cb + 31 >= nk + KB) {                         // wave-uniform
            float L0[4][KB];
            #pragma unroll
            for (int q = 0; q < 4; ++q)
                #pragma unroll
                for (int m = 0; m < KB; ++m) L0[q][m] = s_panel[buf][q*64+ln][m];
            #pragma unroll
            for (int u4 = 0; u4 < 8; ++u4) {
                if (cb + u4*4 >= nk + KB) {               // wave-uniform
                    #pragma unroll
                    for (int m = 0; m < KB; ++m) {
                        const float4 uvv = *reinterpret_cast<const float4*>(&s_U[m][cb + u4*4]);
                        #pragma unroll
                        for (int q = 0; q < 4; ++q) {
                            if (q*64 + 63 >= nk) {        // wave-uniform
                                a[q][u4*4+0] = fmaf(-L0[q][m], uvv.x, a[q][u4*4+0]);
                                a[q][u4*4+1] = fmaf(-L0[q][m], uvv.y, a[q][u4*4+1]);
                                a[q][u4*4+2] = fmaf(-L0[q][m], uvv.z, a[q][u4*4+2]);
                                a[q][u4*4+3] = fmaf(-L0[q][m], uvv.w, a[q][u4*4+3]);
                            }
                        }
                    }
                }
            }
        }
        __syncthreads();                                  // B6
    }

    // ---- logdet = sum log|piv| (f64 accum), sign = parity of negatives ----
    if (tid < 64) {
        double ld = 0.0; int neg = 0;
        #pragma unroll
        for (int q = 0; q < 4; ++q) {
            float pv = s_piv[q*64 + tid];
            ld  += (double)logf(fabsf(pv));
            neg ^= (pv < 0.0f) ? 1 : 0;
        }
        #pragma unroll
        for (int off = 32; off; off >>= 1) {
            ld  += __shfl_xor(ld, off);
            neg ^= __shfl_xor(neg, off);
        }
        if (tid == 0) { out[0] = neg ? -1.0f : 1.0f; out[1] = (float)ld; }
    }
}

extern "C" void kernel_launch(void* const* d_in, const int* in_sizes, int n_in,
                              void* d_out, int out_size, void* d_ws, size_t ws_size,
                              hipStream_t stream)
{
    const float* x  = (const float*)d_in[0];
    const float* W0 = (const float*)d_in[1];
    const float* b0 = (const float*)d_in[2];
    const float* W1 = (const float*)d_in[3];
    const float* b1 = (const float*)d_in[4];
    const float* W2 = (const float*)d_in[5];
    const float* b2 = (const float*)d_in[6];
    float* out    = (float*)d_out;
    float* slater = (float*)d_ws;           // 256*256*4 = 256 KB scratch

    k_mlp_v3<<<512, 512, 0, stream>>>(x, W0, b0, W1, b1, W2, b2, slater);
    k_lu_blk<<<1, 512, 0, stream>>>(slater, out);
}

// Round 18
// 656.038 us; speedup vs baseline: 1.3908x; 1.0530x over previous
//
#include <hip/hip_runtime.h>
#include <math.h>

#define NP 256
#define HID 512
#define KB 8        // LU panel width

typedef short bf16x8 __attribute__((ext_vector_type(8)));
typedef float f32x4v __attribute__((ext_vector_type(4)));

// RNE bf16 with exact residual (v - bf16(v) is exactly representable).
__device__ __forceinline__ short bf16_rne(float v, float& rem) {
    unsigned u = __float_as_uint(v);
    unsigned r = (u + 0x7FFFu + ((u >> 16) & 1u)) & 0xFFFF0000u;
    rem = v - __uint_as_float(r);
    return (short)(r >> 16);
}
// 3-way RNE split: v = h + m + lo + r3, |r3| <= 2^-27 |v| (unbiased).
__device__ __forceinline__ void split3(float v, short& h, short& m, short& lo) {
    float r1, r2;
    h = bf16_rne(v, r1);
    m = bf16_rne(r1, r2);
    unsigned u2 = __float_as_uint(r2);
    lo = (short)((u2 + 0x7FFFu + ((u2 >> 16) & 1u)) >> 16);
}

// v4 MLP (r18): B-tile remap f = fb + 4*col + ft (was fb + ft*16 + col).
// One float4 load now serves all 4 ft for a k-row: B global loads drop
// 4x (32 -> 8 per K-step) and are perfectly coalesced (16 lanes x 16B
// contiguous per g-group). Same (b,f,k) product set, same per-element
// MFMA order -> FP-bit-identical output; absmax must stay exactly 64.0.
// Everything else identical to the passing r15-r17 v3 kernel.
__global__ __launch_bounds__(512, 1) void k_mlp_v4(
    const float* __restrict__ x,  const float* __restrict__ W0,
    const float* __restrict__ b0, const float* __restrict__ W1,
    const float* __restrict__ b1, const float* __restrict__ W2,
    const float* __restrict__ b2, float* __restrict__ slater)
{
    __shared__ __align__(16) short pA[3][2][4][128][8];  // 48 KB
    __shared__ float s_red[8][128];                      // 4 KB
    const int bid  = blockIdx.x;
    const int xcd  = bid & 7;
    const int jj   = bid >> 3;
    const int half = jj & 1;
    const int w    = (xcd << 5) + (jj >> 1);
    const int tid  = threadIdx.x;
    const int wid  = tid >> 6;     // wave 0..7 -> f-slice wid*64
    const int l    = tid & 63;
    const int col  = l & 15;
    const int g    = l >> 4;
    const int fb   = wid * 64;

    f32x4v acc[8][4];
    #pragma unroll
    for (int bt = 0; bt < 8; ++bt)
        #pragma unroll
        for (int ft = 0; ft < 4; ++ft)
            acc[bt][ft] = (f32x4v){0.f, 0.f, 0.f, 0.f};

    // layer-0 mapping: 64 c x 128 b per phase, 16 per thread
    const int bb = tid & 127;
    const int co = tid >> 7;       // 0..3 (wave-pair uniform)
    const int bg = half*128 + bb;
    const float x0 = x[bg*3+0], x1 = x[bg*3+1], x2 = x[bg*3+2];
    const float* W0w = W0 + (size_t)w*3*HID;
    const float* b0w = b0 + (size_t)w*HID;
    // per-lane B base: 4 consecutive f (one float4) covering ft=0..3
    const float* w1c = W1 + (size_t)w*HID*HID + fb + 4*col;

    for (int ph = 0; ph < 8; ++ph) {
        if (ph) __syncthreads();
        // ---- layer 0: split h0 once into packed A-frags ----
        #pragma unroll 4
        for (int pass = 0; pass < 16; ++pass) {
            int cl = co + 4*pass;          // 0..63
            int c  = ph*64 + cl;
            float v = x0*W0w[c] + x1*W0w[HID+c] + x2*W0w[2*HID+c] + b0w[c];
            float t = tanhf(v);
            short h, m, lo; split3(t, h, m, lo);
            int ks = cl >> 5, r32 = cl & 31;
            int gg = (r32 >> 2) & 3;
            int jv = (r32 & 3) + 4*(r32 >> 4);
            pA[0][ks][gg][bb][jv] = h;
            pA[1][ks][gg][bb][jv] = m;
            pA[2][ks][gg][bb][jv] = lo;
        }
        __syncthreads();

        #pragma unroll
        for (int ks = 0; ks < 2; ++ks) {
            // ---- B: 8 float4 loads (one per k-row), split -> all 4 ft ----
            bf16x8 Bh[4], Bm[4], Bl[4];
            const float* bkp = w1c + (size_t)(ph*64 + ks*32 + 4*g)*HID;
            #pragma unroll
            for (int j = 0; j < 8; ++j) {
                int koff = (j&3) + 16*(j>>2);
                float4 bv = *reinterpret_cast<const float4*>(bkp + (size_t)koff*HID);
                short h, m, lo;
                split3(bv.x, h, m, lo); Bh[0][j]=h; Bm[0][j]=m; Bl[0][j]=lo;
                split3(bv.y, h, m, lo); Bh[1][j]=h; Bm[1][j]=m; Bl[1][j]=lo;
                split3(bv.z, h, m, lo); Bh[2][j]=h; Bm[2][j]=m; Bl[2][j]=lo;
                split3(bv.w, h, m, lo); Bh[3][j]=h; Bm[3][j]=m; Bl[3][j]=lo;
            }
            // ---- A-frags in 2 chunks of 4 bt; 6-product MFMA ----
            #pragma unroll
            for (int btc = 0; btc < 2; ++btc) {
                bf16x8 Ah[4], Am[4], Al[4];
                #pragma unroll
                for (int b4 = 0; b4 < 4; ++b4) {
                    int row = (btc*4 + b4)*16 + col;
                    Ah[b4] = *reinterpret_cast<const bf16x8*>(&pA[0][ks][g][row][0]);
                    Am[b4] = *reinterpret_cast<const bf16x8*>(&pA[1][ks][g][row][0]);
                    Al[b4] = *reinterpret_cast<const bf16x8*>(&pA[2][ks][g][row][0]);
                }
                #pragma unroll
                for (int b4 = 0; b4 < 4; ++b4) {
                    const int bt = btc*4 + b4;
                    #pragma unroll
                    for (int ft = 0; ft < 4; ++ft) {
                        acc[bt][ft] = __builtin_amdgcn_mfma_f32_16x16x32_bf16(Ah[b4], Bh[ft], acc[bt][ft], 0,0,0);
                        acc[bt][ft] = __builtin_amdgcn_mfma_f32_16x16x32_bf16(Ah[b4], Bm[ft], acc[bt][ft], 0,0,0);
                        acc[bt][ft] = __builtin_amdgcn_mfma_f32_16x16x32_bf16(Am[b4], Bh[ft], acc[bt][ft], 0,0,0);
                        acc[bt][ft] = __builtin_amdgcn_mfma_f32_16x16x32_bf16(Ah[b4], Bl[ft], acc[bt][ft], 0,0,0);
                        acc[bt][ft] = __builtin_amdgcn_mfma_f32_16x16x32_bf16(Am[b4], Bm[ft], acc[bt][ft], 0,0,0);
                        acc[bt][ft] = __builtin_amdgcn_mfma_f32_16x16x32_bf16(Al[b4], Bh[ft], acc[bt][ft], 0,0,0);
                    }
                }
            }
        }
    }

    // ---- epilogue: tanh(acc+b1).W2, reduce over f, write slater row ----
    // lane's 4 f values are consecutive: f = fb + 4*col + ft -> float4 loads
    const float* b1w = b1 + (size_t)w*HID + fb + 4*col;
    const float* W2w = W2 + (size_t)w*HID + fb + 4*col;
    float4 bb4 = *reinterpret_cast<const float4*>(b1w);
    float4 wt4 = *reinterpret_cast<const float4*>(W2w);
    float bbv[4] = {bb4.x, bb4.y, bb4.z, bb4.w};
    float wtv[4] = {wt4.x, wt4.y, wt4.z, wt4.w};
    #pragma unroll
    for (int bt = 0; bt < 8; ++bt)
        #pragma unroll
        for (int r = 0; r < 4; ++r) {
            float part = 0.f;
            #pragma unroll
            for (int ft = 0; ft < 4; ++ft)
                part += tanhf(acc[bt][ft][r] + bbv[ft]) * wtv[ft];
            part += __shfl_xor(part, 1); part += __shfl_xor(part, 2);
            part += __shfl_xor(part, 4); part += __shfl_xor(part, 8);
            if (col == 0) s_red[wid][bt*16 + g*4 + r] = part;
        }
    __syncthreads();
    if (tid < 128) {
        float s = 0.f;
        #pragma unroll
        for (int wd = 0; wd < 8; ++wd) s += s_red[wd][tid];
        slater[w*NP + half*128 + tid] = s + b2[w];
    }
}

__device__ __forceinline__ float rf_f32(float x) {
    return __uint_as_float(__builtin_amdgcn_readfirstlane(__float_as_uint(x)));
}
__device__ __forceinline__ float rl_f32(float x, int lane) {
    return __uint_as_float(__builtin_amdgcn_readlane(__float_as_uint(x), lane));
}
template<int CTRL>
__device__ __forceinline__ unsigned dpp_u32(unsigned v) {
    return (unsigned)__builtin_amdgcn_update_dpp(0, (int)v, CTRL, 0xF, 0xF, true);
}

// Blocked (KB=8) partially-pivoted f32 LU with panel lookahead.
// Byte-identical to the passing round-17 version (411 us, absmax 64.0).
__global__ __launch_bounds__(512, 1) void k_lu_blk(const float* __restrict__ A,
                                                   float* __restrict__ out)
{
    const int tid  = threadIdx.x;
    const int ln   = tid & 63;      // lane: row-in-quarter
    const int wv   = tid >> 6;      // wave id = 32-col slice (wave-uniform)
    const int cb   = wv * 32;       // col base

    __shared__ float s_panel[2][NP][KB+1];  // double-buffered, stride 9
    __shared__ float s_stage[2*KB][260];
    __shared__ float s_U[KB][260];
    __shared__ int   s_src[NP];
    __shared__ int   s_p[KB];
    __shared__ int   s_uslot[KB];
    __shared__ float s_piv[NP];

    float a[4][32];                       // rows q*64+ln, cols cb..cb+31
    {
        const float4* Ap = reinterpret_cast<const float4*>(A);
        #pragma unroll
        for (int q = 0; q < 4; ++q)
            #pragma unroll
            for (int u = 0; u < 8; ++u) {
                float4 v = Ap[(q*64+ln)*64 + wv*8 + u];
                a[q][u*4+0]=v.x; a[q][u*4+1]=v.y; a[q][u*4+2]=v.z; a[q][u*4+3]=v.w;
            }
    }

    // stage cols [k0s, k0s+8) of this wave's slice into spnl (caller guards wave)
    auto STAGE = [&](int k0s, float (*spnl)[KB+1]) {
        switch ((k0s & 31) >> 3) {
            case 0:
                #pragma unroll
                for (int q = 0; q < 4; ++q)
                    #pragma unroll
                    for (int c = 0; c < KB; ++c) spnl[q*64+ln][c] = a[q][c];
                break;
            case 1:
                #pragma unroll
                for (int q = 0; q < 4; ++q)
                    #pragma unroll
                    for (int c = 0; c < KB; ++c) spnl[q*64+ln][c] = a[q][8+c];
                break;
            case 2:
                #pragma unroll
                for (int q = 0; q < 4; ++q)
                    #pragma unroll
                    for (int c = 0; c < KB; ++c) spnl[q*64+ln][c] = a[q][16+c];
                break;
            default:
                #pragma unroll
                for (int q = 0; q < 4; ++q)
                    #pragma unroll
                    for (int c = 0; c < KB; ++c) spnl[q*64+ln][c] = a[q][24+c];
                break;
        }
    };

    // wave-0 panel factorization (verbatim r15 STEP2, parametrized by buffer)
    auto STEP2 = [&](int k0, float (*spnl)[KB+1]) {
        const int lane = tid;
        float pa[4][KB];
        int   lid[4];
        #pragma unroll
        for (int q = 0; q < 4; ++q) {
            lid[q] = q*64 + lane;
            #pragma unroll
            for (int c = 0; c < KB; ++c) pa[q][c] = spnl[q*64+lane][c];
        }
        int pvt[KB];
        #pragma unroll
        for (int kk = 0; kk < KB; ++kk) {
            const int k = k0 + kk;
            unsigned key = 0u;
            #pragma unroll
            for (int q = 0; q < 4; ++q) {
                unsigned ab = __float_as_uint(pa[q][kk]) & 0x7FFFFFFFu;
                unsigned kq = (ab & 0xFFFFFF00u) | (unsigned)(255 - lid[q]);
                if (lid[q] >= k && kq > key) key = kq;
            }
            { unsigned t;
              t = dpp_u32<0x111>(key); if (t > key) key = t;
              t = dpp_u32<0x112>(key); if (t > key) key = t;
              t = dpp_u32<0x114>(key); if (t > key) key = t;
              t = dpp_u32<0x118>(key); if (t > key) key = t;
              t = dpp_u32<0x142>(key); if (t > key) key = t;
              t = dpp_u32<0x143>(key); if (t > key) key = t;
            }
            const unsigned gk = (unsigned)__builtin_amdgcn_readlane((int)key, 63);
            const int p = 255 - (int)(gk & 0xFFu);
            pvt[kk] = p;
            int myslot = -1;
            #pragma unroll
            for (int q = 0; q < 4; ++q) if (lid[q] == p) myslot = q;
            unsigned long long bal = __ballot(myslot >= 0);
            const int plane = (int)__ffsll((long long)bal) - 1;
            const int pslot = __builtin_amdgcn_readlane(myslot, plane);
            float urow[KB];
            #pragma unroll
            for (int c = 0; c < KB; ++c) {
                float t = (pslot==0) ? pa[0][c] : (pslot==1) ? pa[1][c]
                        : (pslot==2) ? pa[2][c] : pa[3][c];
                urow[c] = rl_f32(t, plane);
            }
            #pragma unroll
            for (int q = 0; q < 4; ++q) {
                int lq = lid[q];
                lid[q] = (lq == k) ? p : (lq == p) ? k : lq;
            }
            const float pv = urow[kk];
            if (lane == 0) s_piv[k] = (p != k) ? -pv : pv;
            const float rp = rf_f32(1.0f / pv);
            #pragma unroll
            for (int q = 0; q < 4; ++q)
                if (lid[q] > k) pa[q][kk] *= rp;
            #pragma unroll
            for (int c = kk+1; c < KB; ++c) {
                #pragma unroll
                for (int q = 0; q < 4; ++q)
                    if (lid[q] > k) pa[q][c] = fmaf(-pa[q][kk], urow[c], pa[q][c]);
            }
        }
        #pragma unroll
        for (int q = 0; q < 4; ++q)
            #pragma unroll
            for (int c = 0; c < KB; ++c) spnl[lid[q]][c] = pa[q][c];
        if (lane == 0) {
            s_p[0]=pvt[0]; s_p[1]=pvt[1]; s_p[2]=pvt[2]; s_p[3]=pvt[3];
            s_p[4]=pvt[4]; s_p[5]=pvt[5]; s_p[6]=pvt[6]; s_p[7]=pvt[7];
        }
        // in-register swap simulation on 16 tracked positions
        int l8 = lane - 8;
        int psel = pvt[0];
        psel = (l8==1)?pvt[1]:psel; psel = (l8==2)?pvt[2]:psel;
        psel = (l8==3)?pvt[3]:psel; psel = (l8==4)?pvt[4]:psel;
        psel = (l8==5)?pvt[5]:psel; psel = (l8==6)?pvt[6]:psel;
        psel = (l8==7)?pvt[7]:psel;
        const int mypos = (lane < 8) ? (k0 + lane) : psel;
        int cur = mypos;
        #pragma unroll
        for (int s = 0; s < KB; ++s) {
            int cA = __builtin_amdgcn_readlane(cur, s);
            int cB = __builtin_amdgcn_readlane(cur, 8+s);
            int ks = k0 + s, ps = pvt[s];
            if (mypos == ks) cur = cB;
            else if (mypos == ps) cur = cA;
        }
        if (lane < 16) s_src[mypos] = cur;
        if (lane < 8) {
            int c = cur, slot = 8;
            slot = (pvt[0]==c)? 8:slot; slot = (pvt[1]==c)? 9:slot;
            slot = (pvt[2]==c)?10:slot; slot = (pvt[3]==c)?11:slot;
            slot = (pvt[4]==c)?12:slot; slot = (pvt[5]==c)?13:slot;
            slot = (pvt[6]==c)?14:slot; slot = (pvt[7]==c)?15:slot;
            if (c >= k0 && c < k0+KB) slot = c - k0;
            s_uslot[lane] = slot;
        }
    };

    // ---- prologue: stage + factorize panel 0 ----
    if (tid < 256) s_src[tid] = tid;
    if (wv == 0) STAGE(0, s_panel[0]);
    __syncthreads();
    if (tid < 64) STEP2(0, s_panel[0]);
    __syncthreads();

    for (int pi = 0; pi < 31; ++pi) {
        const int k0  = pi * KB;
        const int buf = pi & 1;
        const int nk  = k0 + KB;

        int pp[KB];
        #pragma unroll
        for (int s = 0; s < KB; ++s) pp[s] = s_p[s];

        // ---- STEP 3: stage affected rows (pre-swap content, by position) ----
        #pragma unroll
        for (int q = 0; q < 4; ++q) {
            const int iq = q*64 + ln;
            if (iq >= k0 && iq < nk) {
                const int sl = iq - k0;
                #pragma unroll
                for (int u = 0; u < 8; ++u) {
                    float4 v; v.x=a[q][u*4+0]; v.y=a[q][u*4+1];
                    v.z=a[q][u*4+2]; v.w=a[q][u*4+3];
                    *reinterpret_cast<float4*>(&s_stage[sl][cb + u*4]) = v;
                }
            }
            #pragma unroll
            for (int s = 0; s < KB; ++s) {
                if (iq == pp[s]) {
                    #pragma unroll
                    for (int u = 0; u < 8; ++u) {
                        float4 v; v.x=a[q][u*4+0]; v.y=a[q][u*4+1];
                        v.z=a[q][u*4+2]; v.w=a[q][u*4+3];
                        *reinterpret_cast<float4*>(&s_stage[KB+s][cb + u*4]) = v;
                    }
                }
            }
        }
        __syncthreads();                                  // B3

        // ---- STEP 4a: apply row permutation from stage ----
        #pragma unroll
        for (int q = 0; q < 4; ++q) {
            const int iq = q*64 + ln;
            const int sr = s_src[iq];
            if (sr != iq) {
                int slot = KB;
                #pragma unroll
                for (int s = 0; s < KB; ++s) slot = (pp[s]==sr) ? KB+s : slot;
                if (sr >= k0 && sr < nk) slot = sr - k0;
                #pragma unroll
                for (int u = 0; u < 8; ++u) {
                    float4 v = *reinterpret_cast<const float4*>(&s_stage[slot][cb + u*4]);
                    a[q][u*4+0]=v.x; a[q][u*4+1]=v.y; a[q][u*4+2]=v.z; a[q][u*4+3]=v.w;
                }
            }
        }
        // ---- STEP 4b: TRSM of U block, column-parallel (tid<256) ----
        if (tid < 256) {
            const int j = tid;
            int us[KB];
            #pragma unroll
            for (int m = 0; m < KB; ++m) us[m] = s_uslot[m];
            float uv[KB];
            #pragma unroll
            for (int m = 0; m < KB; ++m) {
                float v = s_stage[us[m]][j];
                #pragma unroll
                for (int s = 0; s < KB; ++s)
                    if (s < m) v = fmaf(-s_panel[buf][k0+m][s], uv[s], v);
                uv[m] = v;
                s_U[m][j] = v;
            }
        }
        __syncthreads();                                  // B4

        // ---- STEP 5a: owner wave updates next-panel cols [nk, nk+8),
        //      stages them into s_panel[buf^1]; s_src re-init ----
        if (tid < 256) s_src[tid] = tid;
        if (wv == (nk >> 5)) {
            float L0[4][KB];
            #pragma unroll
            for (int q = 0; q < 4; ++q)
                #pragma unroll
                for (int m = 0; m < KB; ++m) L0[q][m] = s_panel[buf][q*64+ln][m];
            #pragma unroll
            for (int u4 = 0; u4 < 8; ++u4) {
                if (cb + u4*4 >= nk && cb + u4*4 < nk + KB) {   // wave-uniform
                    #pragma unroll
                    for (int m = 0; m < KB; ++m) {
                        const float4 uvv = *reinterpret_cast<const float4*>(&s_U[m][cb + u4*4]);
                        #pragma unroll
                        for (int q = 0; q < 4; ++q) {
                            if (q*64 + 63 >= nk) {              // wave-uniform
                                a[q][u4*4+0] = fmaf(-L0[q][m], uvv.x, a[q][u4*4+0]);
                                a[q][u4*4+1] = fmaf(-L0[q][m], uvv.y, a[q][u4*4+1]);
                                a[q][u4*4+2] = fmaf(-L0[q][m], uvv.z, a[q][u4*4+2]);
                                a[q][u4*4+3] = fmaf(-L0[q][m], uvv.w, a[q][u4*4+3]);
                            }
                        }
                    }
                }
            }
            STAGE(nk, s_panel[buf ^ 1]);
        }
        __syncthreads();                                  // B5

        // ---- wave0: STEP2(next panel)  ||  all waves: STEP5b ----
        if (tid < 64) STEP2(nk, s_panel[buf ^ 1]);
        if (cb + 31 >= nk + KB) {                         // wave-uniform
            float L0[4][KB];
            #pragma unroll
            for (int q = 0; q < 4; ++q)
                #pragma unroll
                for (int m = 0; m < KB; ++m) L0[q][m] = s_panel[buf][q*64+ln][m];
            #pragma unroll
            for (int u4 = 0; u4 < 8; ++u4) {
                if (cb + u4*4 >= nk + KB) {               // wave-uniform
                    #pragma unroll
                    for (int m = 0; m < KB; ++m) {
                        const float4 uvv = *reinterpret_cast<const float4*>(&s_U[m][cb + u4*4]);
                        #pragma unroll
                        for (int q = 0; q < 4; ++q) {
                            if (q*64 + 63 >= nk) {        // wave-uniform
                                a[q][u4*4+0] = fmaf(-L0[q][m], uvv.x, a[q][u4*4+0]);
                                a[q][u4*4+1] = fmaf(-L0[q][m], uvv.y, a[q][u4*4+1]);
                                a[q][u4*4+2] = fmaf(-L0[q][m], uvv.z, a[q][u4*4+2]);
                                a[q][u4*4+3] = fmaf(-L0[q][m], uvv.w, a[q][u4*4+3]);
                            }
                        }
                    }
                }
            }
        }
        __syncthreads();                                  // B6
    }

    // ---- logdet = sum log|piv| (f64 accum), sign = parity of negatives ----
    if (tid < 64) {
        double ld = 0.0; int neg = 0;
        #pragma unroll
        for (int q = 0; q < 4; ++q) {
            float pv = s_piv[q*64 + tid];
            ld  += (double)logf(fabsf(pv));
            neg ^= (pv < 0.0f) ? 1 : 0;
        }
        #pragma unroll
        for (int off = 32; off; off >>= 1) {
            ld  += __shfl_xor(ld, off);
            neg ^= __shfl_xor(neg, off);
        }
        if (tid == 0) { out[0] = neg ? -1.0f : 1.0f; out[1] = (float)ld; }
    }
}

extern "C" void kernel_launch(void* const* d_in, const int* in_sizes, int n_in,
                              void* d_out, int out_size, void* d_ws, size_t ws_size,
                              hipStream_t stream)
{
    const float* x  = (const float*)d_in[0];
    const float* W0 = (const float*)d_in[1];
    const float* b0 = (const float*)d_in[2];
    const float* W1 = (const float*)d_in[3];
    const float* b1 = (const float*)d_in[4];
    const float* W2 = (const float*)d_in[5];
    const float* b2 = (const float*)d_in[6];
    float* out    = (float*)d_out;
    float* slater = (float*)d_ws;           // 256*256*4 = 256 KB scratch

    k_mlp_v4<<<512, 512, 0, stream>>>(x, W0, b0, W1, b1, W2, b2, slater);
    k_lu_blk<<<1, 512, 0, stream>>>(slater, out);
}